// Round 13
// baseline (241.842 us; speedup 1.0000x reference)
//
#include <hip/hip_runtime.h>
#include <hip/hip_bf16.h>

#define NN 8192
#define NE 262144
#define CAP 96
#define AWK 136   // 128 + 8 pad (ushorts)

typedef __attribute__((ext_vector_type(8))) __bf16 bf16x8;
typedef __attribute__((ext_vector_type(4))) float f32x4;

__device__ __forceinline__ ushort f2b(float v) {
    __hip_bfloat16 b = __float2bfloat16(v);
    return *reinterpret_cast<ushort*>(&b);
}
__device__ __forceinline__ uint pack2(float lo, float hi) {
    return (uint)f2b(lo) | ((uint)f2b(hi) << 16);
}
__device__ __forceinline__ float b2f(ushort u) {
    return __uint_as_float(((uint)u) << 16);
}

// ---------------------------------------------------------------------------
// 64x64 GEMM tile, BK=128: C[by,bx] = act(A @ BT^T + addend)
// ---------------------------------------------------------------------------
template <bool A1F32, bool RELU, int OUTMODE, bool ADDC>
__device__ __forceinline__ void gemm_tile64(
    int by, int bx, const void* __restrict__ Av, const ushort* __restrict__ BT,
    int K, const float* __restrict__ bias, const ushort* __restrict__ cin,
    float* __restrict__ Cf, ushort* __restrict__ Cb, int N,
    ushort* As, ushort* Bs) {
    const int tid = threadIdx.x, lane = tid & 63, wave = tid >> 6;
    const int wm = (wave >> 1) * 32, wn = (wave & 1) * 32;
    const int r16 = lane & 15, kb = lane >> 4;
    const int m0 = by * 64, n0 = bx * 64;

    f32x4 acc[2][2];
#pragma unroll
    for (int i = 0; i < 2; ++i)
#pragma unroll
        for (int j = 0; j < 2; ++j) acc[i][j] = (f32x4)(0.f);

    for (int k0 = 0; k0 < K; k0 += 128) {
        if constexpr (A1F32) {
            const float* A = (const float*)Av;
#pragma unroll
            for (int rep = 0; rep < 8; ++rep) {
                int id = rep * 256 + tid;
                int row = id >> 5, c = id & 31;
                float4 f = *(const float4*)&A[(size_t)(m0 + row) * K + k0 + c * 4];
                uint2 o; o.x = pack2(f.x, f.y); o.y = pack2(f.z, f.w);
                *(uint2*)&As[row * AWK + c * 4] = o;
            }
        } else {
            const ushort* A = (const ushort*)Av;
#pragma unroll
            for (int rep = 0; rep < 4; ++rep) {
                int id = rep * 256 + tid;
                int row = id >> 4, c = id & 15;
                *(bf16x8*)&As[row * AWK + c * 8] =
                    *(const bf16x8*)&A[(size_t)(m0 + row) * K + k0 + c * 8];
            }
        }
#pragma unroll
        for (int rep = 0; rep < 4; ++rep) {
            int id = rep * 256 + tid;
            int row = id >> 4, c = id & 15;
            *(bf16x8*)&Bs[row * AWK + c * 8] =
                *(const bf16x8*)&BT[(size_t)(n0 + row) * K + k0 + c * 8];
        }
        __syncthreads();
#pragma unroll
        for (int kc = 0; kc < 4; ++kc) {
            bf16x8 a[2], b[2];
#pragma unroll
            for (int i = 0; i < 2; ++i)
                a[i] = *(const bf16x8*)&As[(wm + 16 * i + r16) * AWK + kc * 32 + kb * 8];
#pragma unroll
            for (int j = 0; j < 2; ++j)
                b[j] = *(const bf16x8*)&Bs[(wn + 16 * j + r16) * AWK + kc * 32 + kb * 8];
#pragma unroll
            for (int i = 0; i < 2; ++i)
#pragma unroll
                for (int j = 0; j < 2; ++j)
                    acc[i][j] = __builtin_amdgcn_mfma_f32_16x16x32_bf16(a[i], b[j], acc[i][j], 0, 0, 0);
        }
        __syncthreads();
    }

#pragma unroll
    for (int i = 0; i < 2; ++i) {
#pragma unroll
        for (int j = 0; j < 2; ++j) {
            int col = n0 + wn + 16 * j + r16;
            float bv = ADDC ? 0.f : bias[col];
#pragma unroll
            for (int r = 0; r < 4; ++r) {
                int row = m0 + wm + 16 * i + kb * 4 + r;
                float v = acc[i][j][r];
                if constexpr (ADDC) v += b2f(cin[(size_t)row * N + col]);
                else v += bv;
                if (RELU) v = fmaxf(v, 0.f);
                if (OUTMODE != 0) Cf[(size_t)row * N + col] = v;
                if (OUTMODE != 1) Cb[(size_t)row * N + col] = f2b(v);
            }
        }
    }
}

// ---------------------------------------------------------------------------
// segmax for 4 nodes (1 wave each)
// ---------------------------------------------------------------------------
template <int DIN>
__device__ __forceinline__ void seg4(
    int grp, const ushort* __restrict__ Pin, const int* __restrict__ cnt,
    const uint2* __restrict__ slots, ushort* __restrict__ G) {
    constexpr int FPL = DIN / 64;
    const int lane = threadIdx.x & 63, wave = threadIdx.x >> 6;
    int node = grp * 4 + wave;
    int f0 = lane * FPL;
    int n = cnt[node]; if (n > CAP) n = CAP;
    const uint2* sl = &slots[(size_t)node * CAP];
    float mx[FPL];
#pragma unroll
    for (int i = 0; i < FPL; ++i) mx[i] = 0.f;
    auto upd = [&](uint s, float w) {
        const uint* hp = (const uint*)&Pin[(size_t)s * DIN + f0];
#pragma unroll
        for (int c = 0; c < FPL / 2; ++c) {
            uint u = hp[c];
            float lo = __uint_as_float(u << 16);
            float hi = __uint_as_float(u & 0xffff0000u);
            mx[2 * c] = fmaxf(mx[2 * c], lo * w);
            mx[2 * c + 1] = fmaxf(mx[2 * c + 1], hi * w);
        }
    };
    int e = 0;
    for (; e + 8 <= n; e += 8) {
        uint2 d[8];
#pragma unroll
        for (int t = 0; t < 8; ++t) d[t] = sl[e + t];
#pragma unroll
        for (int t = 0; t < 8; ++t) upd(d[t].x, __uint_as_float(d[t].y));
    }
    for (; e < n; ++e) { uint2 d = sl[e]; upd(d.x, __uint_as_float(d.y)); }
    uint* gp = (uint*)&G[(size_t)node * DIN + f0];
#pragma unroll
    for (int c = 0; c < FPL / 2; ++c) gp[c] = pack2(mx[2 * c], mx[2 * c + 1]);
}

// ---------------------------------------------------------------------------
// prep: zero cnt (blocks 0..31) + 9 weight transposes ([K][N] f32 -> [N][K] bf16)
// ---------------------------------------------------------------------------
struct PrepArgs {
    int* cnt;
    const float* w[9]; ushort* wt[9];
};

__global__ __launch_bounds__(256) void prep_k(PrepArgs a) {
    const int bid = blockIdx.x, tid = threadIdx.x;
    if (bid < 32) { a.cnt[bid * 256 + tid] = 0; return; }
    int id = (bid - 32) * 256 + tid;     // 376832 total
    if (id >= 376832) return;
    const int cum[10] = {0, 16384, 49152, 81920, 147456, 212992, 278528, 344064, 360448, 376832};
    const int KK[9] = {128, 128, 128, 256, 256, 256, 256, 256, 256};
    const int LN[9] = {7, 8, 8, 8, 8, 8, 8, 6, 6};   // log2(N)
    int m = 0;
#pragma unroll
    for (int t = 1; t < 9; ++t) m += (id >= cum[t]);
    int local = id - cum[m];
    int K = KK[m], ln = LN[m];
    int k = local >> ln, n = local & ((1 << ln) - 1);
    a.wt[m][n * K + k] = f2b(a.w[m][local]);
}

// ---------------------------------------------------------------------------
// scatter || pool1, INTERLEAVED (bid%5==4 -> pool1 tile, else scatter chunk).
// ---------------------------------------------------------------------------
__global__ __launch_bounds__(256, 4) void scat_pool1_k(
    const int* __restrict__ src, const int* __restrict__ dst,
    const float* __restrict__ ew, int* __restrict__ cnt, uint2* __restrict__ slots,
    const float* __restrict__ feat, const ushort* __restrict__ WpT,
    const float* __restrict__ bp, ushort* __restrict__ P) {
    __shared__ __align__(16) ushort As[64 * AWK];
    __shared__ __align__(16) ushort Bs[64 * AWK];
    const int g = blockIdx.x / 5, r = blockIdx.x % 5;
    if (r == 4) {   // pool1 tile g = 0..255
        gemm_tile64<true, true, 0, false>(g >> 1, g & 1, feat, WpT, 128,
                                          bp, nullptr, nullptr, P, 128, As, Bs);
    } else {        // scatter chunk g*4+r = 0..1023
        int e = (g * 4 + r) * 256 + threadIdx.x;
        int d = dst[e];
        int p = atomicAdd(&cnt[d], 1);
        if (p < CAP) slots[(size_t)d * CAP + p] = make_uint2((uint)src[e], __float_as_uint(ew[e]));
    }
}

// ---------------------------------------------------------------------------
// seg || self, INTERLEAVED: bid%(RATIO+1)==RATIO -> self tile, else seg group.
// ---------------------------------------------------------------------------
template <int DIN, int RATIO, bool A1F32, int KSELF, int NSELF>
__global__ __launch_bounds__(256, 4) void seg_self_k(
    const ushort* __restrict__ Pin, const int* __restrict__ cnt,
    const uint2* __restrict__ slots, ushort* __restrict__ G,
    const void* __restrict__ Av, const ushort* __restrict__ WsT,
    const float* __restrict__ bias, ushort* __restrict__ Cs) {
    __shared__ __align__(16) ushort As[64 * AWK];
    __shared__ __align__(16) ushort Bs[64 * AWK];
    const int g = blockIdx.x / (RATIO + 1), r = blockIdx.x % (RATIO + 1);
    if (r == RATIO) {
        constexpr int NBX = NSELF / 64;
        gemm_tile64<A1F32, false, 0, false>(g / NBX, g % NBX, Av, WsT, KSELF,
                                            bias, nullptr, nullptr, Cs, NSELF, As, Bs);
    } else {
        seg4<DIN>(g * RATIO + r, Pin, cnt, slots, G);
    }
}

// ---------------------------------------------------------------------------
// plain GEMM wrapper
// ---------------------------------------------------------------------------
template <bool A1F32, bool RELU, int OUTMODE, bool ADDC>
__global__ __launch_bounds__(256, 4) void gemm_k(
    const void* __restrict__ Av, const ushort* __restrict__ BT, int K,
    const float* __restrict__ bias, const ushort* __restrict__ cin,
    float* __restrict__ Cf, ushort* __restrict__ Cb, int N) {
    __shared__ __align__(16) ushort As[64 * AWK];
    __shared__ __align__(16) ushort Bs[64 * AWK];
    gemm_tile64<A1F32, RELU, OUTMODE, ADDC>(blockIdx.y, blockIdx.x, Av, BT, K,
                                            bias, cin, Cf, Cb, N, As, Bs);
}

// ---------------------------------------------------------------------------
// adj = H @ H^T, H [8192][64] bf16, C fp32. 128x128 tile, K=64 single stage.
// Epilogue restaged through LDS -> full-line (512B/row) float4 stores.
// ---------------------------------------------------------------------------
__global__ __launch_bounds__(256) void aat_k(const ushort* __restrict__ H,
                                             float* __restrict__ C) {
    __shared__ __align__(16) ushort As[128 * 72];
    __shared__ __align__(16) ushort Bs[128 * 72];
    int tid = threadIdx.x, lane = tid & 63, wave = tid >> 6;
    int wm = (wave >> 1) * 64, wn = (wave & 1) * 64;
    int r16 = lane & 15, kb = lane >> 4;
    int m0 = blockIdx.y * 128, n0 = blockIdx.x * 128;

#pragma unroll
    for (int rep = 0; rep < 4; ++rep) {
        int id = rep * 256 + tid;
        int row = id >> 3, c = id & 7;
        *(bf16x8*)&As[row * 72 + c * 8] = *(const bf16x8*)&H[(size_t)(m0 + row) * 64 + c * 8];
        *(bf16x8*)&Bs[row * 72 + c * 8] = *(const bf16x8*)&H[(size_t)(n0 + row) * 64 + c * 8];
    }
    __syncthreads();

    f32x4 acc[4][4];
#pragma unroll
    for (int i = 0; i < 4; ++i)
#pragma unroll
        for (int j = 0; j < 4; ++j) acc[i][j] = (f32x4)(0.f);

#pragma unroll
    for (int kc = 0; kc < 2; ++kc) {
        bf16x8 a[4], b[4];
#pragma unroll
        for (int i = 0; i < 4; ++i)
            a[i] = *(const bf16x8*)&As[(wm + 16 * i + r16) * 72 + kc * 32 + kb * 8];
#pragma unroll
        for (int j = 0; j < 4; ++j)
            b[j] = *(const bf16x8*)&Bs[(wn + 16 * j + r16) * 72 + kc * 32 + kb * 8];
#pragma unroll
        for (int i = 0; i < 4; ++i)
#pragma unroll
            for (int j = 0; j < 4; ++j)
                acc[i][j] = __builtin_amdgcn_mfma_f32_16x16x32_bf16(a[i], b[j], acc[i][j], 0, 0, 0);
    }

    // epilogue: restage 32 rows x 128 cols f32 per pass through LDS (reuses As/Bs),
    // then write 512B-contiguous rows as float4.
    float* st = (float*)As;             // needs 32*132*4 = 16896 B <= 36 KB
#pragma unroll 1
    for (int i = 0; i < 4; ++i) {
        __syncthreads();
#pragma unroll
        for (int j = 0; j < 4; ++j)
#pragma unroll
            for (int r = 0; r < 4; ++r)
                st[((wm >> 2) + kb * 4 + r) * 132 + wn + 16 * j + r16] = acc[i][j][r];
        __syncthreads();
#pragma unroll
        for (int rep = 0; rep < 4; ++rep) {
            int idx = rep * 256 + tid;       // 0..1023
            int sr = idx >> 5;               // 0..31
            int c4 = idx & 31;               // 0..31 float4 within row
            size_t grow = m0 + ((sr >> 4) ? 64 : 0) + 16 * i + (sr & 15);
            float4 v = *(float4*)&st[sr * 132 + c4 * 4];
            *(float4*)&C[grow * NN + n0 + c4 * 4] = v;
        }
    }
}

// ---------------------------------------------------------------------------
extern "C" void kernel_launch(void* const* d_in, const int* in_sizes, int n_in,
                              void* d_out, int out_size, void* d_ws, size_t ws_size,
                              hipStream_t stream) {
    const float* feat = (const float*)d_in[0];
    const int* src = (const int*)d_in[1];
    const int* dst = (const int*)d_in[2];
    const float* ew = (const float*)d_in[3];
    const float* Wp1 = (const float*)d_in[5];
    const float* bp1 = (const float*)d_in[6];
    const float* Ws1 = (const float*)d_in[7];
    const float* Wn1 = (const float*)d_in[8];
    const float* b1  = (const float*)d_in[9];
    const float* Wp2 = (const float*)d_in[10];
    const float* bp2 = (const float*)d_in[11];
    const float* Ws2 = (const float*)d_in[12];
    const float* Wn2 = (const float*)d_in[13];
    const float* b2  = (const float*)d_in[14];
    const float* Wp3 = (const float*)d_in[15];
    const float* bp3 = (const float*)d_in[16];
    const float* Ws3 = (const float*)d_in[17];
    const float* Wn3 = (const float*)d_in[18];
    const float* b3  = (const float*)d_in[19];

    float* out = (float*)d_out;          // hd fp32 [8192][64]
    float* adj = out + (size_t)NN * 64;  // adj fp32 [8192][8192]

    char* ws = (char*)d_ws;
    int* cnt      = (int*)(ws + 0x0);          // 32 KB
    uint2* slots  = (uint2*)(ws + 0x10000);    // 6 MB
    ushort* Wp1T = (ushort*)(ws + 0x620000);
    ushort* Ws1T = (ushort*)(ws + 0x628000);
    ushort* Wn1T = (ushort*)(ws + 0x638000);
    ushort* Wp2T = (ushort*)(ws + 0x648000);
    ushort* Ws2T = (ushort*)(ws + 0x668000);
    ushort* Wn2T = (ushort*)(ws + 0x688000);
    ushort* Wp3T = (ushort*)(ws + 0x6A8000);
    ushort* Ws3T = (ushort*)(ws + 0x6C8000);
    ushort* Wn3T = (ushort*)(ws + 0x6D0000);
    ushort* P  = (ushort*)(ws + 0x700000);     // pool bf16 [N][<=256]
    ushort* G  = (ushort*)(ws + 0xB00000);     // agg bf16 [N][<=256]
    ushort* X  = (ushort*)(ws + 0xF00000);     // x2 bf16 [N][256]
    ushort* Y  = (ushort*)(ws + 0x1300000);    // x3 bf16 [N][256]
    ushort* Cs = (ushort*)(ws + 0x1700000);    // self bf16 [N][<=256]
    ushort* hdb = (ushort*)(ws + 0x1B00000);   // hd bf16 [N][64]

    // 1) prep: zero cnt + weight transposes
    PrepArgs pa;
    pa.cnt = cnt;
    const float* wsrc[9] = {Wp1, Ws1, Wn1, Wp2, Ws2, Wn2, Wp3, Ws3, Wn3};
    ushort* wdst[9] = {Wp1T, Ws1T, Wn1T, Wp2T, Ws2T, Wn2T, Wp3T, Ws3T, Wn3T};
    for (int i = 0; i < 9; ++i) { pa.w[i] = wsrc[i]; pa.wt[i] = wdst[i]; }
    prep_k<<<32 + 1472, 256, 0, stream>>>(pa);

    // 2) scatter || pool1 (interleaved)
    scat_pool1_k<<<1280, 256, 0, stream>>>(src, dst, ew, cnt, slots, feat, Wp1T, bp1, P);

    // layer 1 (128 -> 256)
    seg_self_k<128, 4, true, 128, 256><<<2560, 256, 0, stream>>>(
        P, cnt, slots, G, feat, Ws1T, b1, Cs);
    gemm_k<false, true, 0, true><<<dim3(4, 128), 256, 0, stream>>>(
        G, Wn1T, 128, nullptr, Cs, nullptr, X, 256);                  // X = relu(G@Wn1 + Cs)

    // layer 2 (256 -> 256)
    gemm_k<false, true, 0, false><<<dim3(4, 128), 256, 0, stream>>>(
        X, Wp2T, 256, bp2, nullptr, nullptr, P, 256);                 // pool2
    seg_self_k<256, 4, false, 256, 256><<<2560, 256, 0, stream>>>(
        P, cnt, slots, G, X, Ws2T, b2, Cs);
    gemm_k<false, true, 0, true><<<dim3(4, 128), 256, 0, stream>>>(
        G, Wn2T, 256, nullptr, Cs, nullptr, Y, 256);                  // Y

    // layer 3 (256 -> 64)
    gemm_k<false, true, 0, false><<<dim3(4, 128), 256, 0, stream>>>(
        Y, Wp3T, 256, bp3, nullptr, nullptr, P, 256);                 // pool3
    seg_self_k<256, 16, false, 256, 64><<<2176, 256, 0, stream>>>(
        P, cnt, slots, G, Y, Ws3T, b3, Cs);
    gemm_k<false, true, 2, true><<<dim3(1, 128), 256, 0, stream>>>(
        G, Wn3T, 256, nullptr, Cs, out, hdb, 64);                     // hd fp32 + bf16

    // adj = hd @ hd^T
    aat_k<<<dim3(NN / 128, NN / 128), 256, 0, stream>>>(hdb, adj);
}

// Round 14
// 163.126 us; speedup vs baseline: 1.4825x; 1.4825x over previous
//
#include <hip/hip_runtime.h>
#include <hip/hip_bf16.h>

#define NN 8192
#define NE 262144
#define CAP 96
#define AWK 136   // 128 + 8 pad (ushorts)

typedef __attribute__((ext_vector_type(8))) __bf16 bf16x8;
typedef __attribute__((ext_vector_type(4))) float f32x4;

__device__ __forceinline__ ushort f2b(float v) {
    __hip_bfloat16 b = __float2bfloat16(v);
    return *reinterpret_cast<ushort*>(&b);
}
__device__ __forceinline__ uint pack2(float lo, float hi) {
    return (uint)f2b(lo) | ((uint)f2b(hi) << 16);
}
__device__ __forceinline__ float b2f(ushort u) {
    return __uint_as_float(((uint)u) << 16);
}

// ---------------------------------------------------------------------------
// 64x64 GEMM tile, BK=128: C[by,bx] = act(A @ BT^T + addend)
// ---------------------------------------------------------------------------
template <bool A1F32, bool RELU, int OUTMODE, bool ADDC>
__device__ __forceinline__ void gemm_tile64(
    int by, int bx, const void* __restrict__ Av, const ushort* __restrict__ BT,
    int K, const float* __restrict__ bias, const ushort* __restrict__ cin,
    float* __restrict__ Cf, ushort* __restrict__ Cb, int N,
    ushort* As, ushort* Bs) {
    const int tid = threadIdx.x, lane = tid & 63, wave = tid >> 6;
    const int wm = (wave >> 1) * 32, wn = (wave & 1) * 32;
    const int r16 = lane & 15, kb = lane >> 4;
    const int m0 = by * 64, n0 = bx * 64;

    f32x4 acc[2][2];
#pragma unroll
    for (int i = 0; i < 2; ++i)
#pragma unroll
        for (int j = 0; j < 2; ++j) acc[i][j] = (f32x4)(0.f);

    for (int k0 = 0; k0 < K; k0 += 128) {
        if constexpr (A1F32) {
            const float* A = (const float*)Av;
#pragma unroll
            for (int rep = 0; rep < 8; ++rep) {
                int id = rep * 256 + tid;
                int row = id >> 5, c = id & 31;
                float4 f = *(const float4*)&A[(size_t)(m0 + row) * K + k0 + c * 4];
                uint2 o; o.x = pack2(f.x, f.y); o.y = pack2(f.z, f.w);
                *(uint2*)&As[row * AWK + c * 4] = o;
            }
        } else {
            const ushort* A = (const ushort*)Av;
#pragma unroll
            for (int rep = 0; rep < 4; ++rep) {
                int id = rep * 256 + tid;
                int row = id >> 4, c = id & 15;
                *(bf16x8*)&As[row * AWK + c * 8] =
                    *(const bf16x8*)&A[(size_t)(m0 + row) * K + k0 + c * 8];
            }
        }
#pragma unroll
        for (int rep = 0; rep < 4; ++rep) {
            int id = rep * 256 + tid;
            int row = id >> 4, c = id & 15;
            *(bf16x8*)&Bs[row * AWK + c * 8] =
                *(const bf16x8*)&BT[(size_t)(n0 + row) * K + k0 + c * 8];
        }
        __syncthreads();
#pragma unroll
        for (int kc = 0; kc < 4; ++kc) {
            bf16x8 a[2], b[2];
#pragma unroll
            for (int i = 0; i < 2; ++i)
                a[i] = *(const bf16x8*)&As[(wm + 16 * i + r16) * AWK + kc * 32 + kb * 8];
#pragma unroll
            for (int j = 0; j < 2; ++j)
                b[j] = *(const bf16x8*)&Bs[(wn + 16 * j + r16) * AWK + kc * 32 + kb * 8];
#pragma unroll
            for (int i = 0; i < 2; ++i)
#pragma unroll
                for (int j = 0; j < 2; ++j)
                    acc[i][j] = __builtin_amdgcn_mfma_f32_16x16x32_bf16(a[i], b[j], acc[i][j], 0, 0, 0);
        }
        __syncthreads();
    }

#pragma unroll
    for (int i = 0; i < 2; ++i) {
#pragma unroll
        for (int j = 0; j < 2; ++j) {
            int col = n0 + wn + 16 * j + r16;
            float bv = ADDC ? 0.f : bias[col];
#pragma unroll
            for (int r = 0; r < 4; ++r) {
                int row = m0 + wm + 16 * i + kb * 4 + r;
                float v = acc[i][j][r];
                if constexpr (ADDC) v += b2f(cin[(size_t)row * N + col]);
                else v += bv;
                if (RELU) v = fmaxf(v, 0.f);
                if (OUTMODE != 0) Cf[(size_t)row * N + col] = v;
                if (OUTMODE != 1) Cb[(size_t)row * N + col] = f2b(v);
            }
        }
    }
}

// ---------------------------------------------------------------------------
// segmax for 4 nodes (1 wave each)
// ---------------------------------------------------------------------------
template <int DIN>
__device__ __forceinline__ void seg4(
    int grp, const ushort* __restrict__ Pin, const int* __restrict__ cnt,
    const uint2* __restrict__ slots, ushort* __restrict__ G) {
    constexpr int FPL = DIN / 64;
    const int lane = threadIdx.x & 63, wave = threadIdx.x >> 6;
    int node = grp * 4 + wave;
    int f0 = lane * FPL;
    int n = cnt[node]; if (n > CAP) n = CAP;
    const uint2* sl = &slots[(size_t)node * CAP];
    float mx[FPL];
#pragma unroll
    for (int i = 0; i < FPL; ++i) mx[i] = 0.f;
    auto upd = [&](uint s, float w) {
        const uint* hp = (const uint*)&Pin[(size_t)s * DIN + f0];
#pragma unroll
        for (int c = 0; c < FPL / 2; ++c) {
            uint u = hp[c];
            float lo = __uint_as_float(u << 16);
            float hi = __uint_as_float(u & 0xffff0000u);
            mx[2 * c] = fmaxf(mx[2 * c], lo * w);
            mx[2 * c + 1] = fmaxf(mx[2 * c + 1], hi * w);
        }
    };
    int e = 0;
    for (; e + 8 <= n; e += 8) {
        uint2 d[8];
#pragma unroll
        for (int t = 0; t < 8; ++t) d[t] = sl[e + t];
#pragma unroll
        for (int t = 0; t < 8; ++t) upd(d[t].x, __uint_as_float(d[t].y));
    }
    for (; e < n; ++e) { uint2 d = sl[e]; upd(d.x, __uint_as_float(d.y)); }
    uint* gp = (uint*)&G[(size_t)node * DIN + f0];
#pragma unroll
    for (int c = 0; c < FPL / 2; ++c) gp[c] = pack2(mx[2 * c], mx[2 * c + 1]);
}

// ---------------------------------------------------------------------------
// prep: zero cnt (blocks 0..31) + 9 weight transposes ([K][N] f32 -> [N][K] bf16)
// ---------------------------------------------------------------------------
struct PrepArgs {
    int* cnt;
    const float* w[9]; ushort* wt[9];
};

__global__ __launch_bounds__(256) void prep_k(PrepArgs a) {
    const int bid = blockIdx.x, tid = threadIdx.x;
    if (bid < 32) { a.cnt[bid * 256 + tid] = 0; return; }
    int id = (bid - 32) * 256 + tid;     // 376832 total
    if (id >= 376832) return;
    const int cum[10] = {0, 16384, 49152, 81920, 147456, 212992, 278528, 344064, 360448, 376832};
    const int KK[9] = {128, 128, 128, 256, 256, 256, 256, 256, 256};
    const int LN[9] = {7, 8, 8, 8, 8, 8, 8, 6, 6};   // log2(N)
    int m = 0;
#pragma unroll
    for (int t = 1; t < 9; ++t) m += (id >= cum[t]);
    int local = id - cum[m];
    int K = KK[m], ln = LN[m];
    int k = local >> ln, n = local & ((1 << ln) - 1);
    a.wt[m][n * K + k] = f2b(a.w[m][local]);
}

// ---------------------------------------------------------------------------
// scatter || pool1, INTERLEAVED (bid%5==4 -> pool1 tile, else scatter chunk).
// ---------------------------------------------------------------------------
__global__ __launch_bounds__(256, 4) void scat_pool1_k(
    const int* __restrict__ src, const int* __restrict__ dst,
    const float* __restrict__ ew, int* __restrict__ cnt, uint2* __restrict__ slots,
    const float* __restrict__ feat, const ushort* __restrict__ WpT,
    const float* __restrict__ bp, ushort* __restrict__ P) {
    __shared__ __align__(16) ushort As[64 * AWK];
    __shared__ __align__(16) ushort Bs[64 * AWK];
    const int g = blockIdx.x / 5, r = blockIdx.x % 5;
    if (r == 4) {   // pool1 tile g = 0..255
        gemm_tile64<true, true, 0, false>(g >> 1, g & 1, feat, WpT, 128,
                                          bp, nullptr, nullptr, P, 128, As, Bs);
    } else {        // scatter chunk g*4+r = 0..1023
        int e = (g * 4 + r) * 256 + threadIdx.x;
        int d = dst[e];
        int p = atomicAdd(&cnt[d], 1);
        if (p < CAP) slots[(size_t)d * CAP + p] = make_uint2((uint)src[e], __float_as_uint(ew[e]));
    }
}

// ---------------------------------------------------------------------------
// seg || self, INTERLEAVED: bid%(RATIO+1)==RATIO -> self tile, else seg group.
// ---------------------------------------------------------------------------
template <int DIN, int RATIO, bool A1F32, int KSELF, int NSELF>
__global__ __launch_bounds__(256, 4) void seg_self_k(
    const ushort* __restrict__ Pin, const int* __restrict__ cnt,
    const uint2* __restrict__ slots, ushort* __restrict__ G,
    const void* __restrict__ Av, const ushort* __restrict__ WsT,
    const float* __restrict__ bias, ushort* __restrict__ Cs) {
    __shared__ __align__(16) ushort As[64 * AWK];
    __shared__ __align__(16) ushort Bs[64 * AWK];
    const int g = blockIdx.x / (RATIO + 1), r = blockIdx.x % (RATIO + 1);
    if (r == RATIO) {
        constexpr int NBX = NSELF / 64;
        gemm_tile64<A1F32, false, 0, false>(g / NBX, g % NBX, Av, WsT, KSELF,
                                            bias, nullptr, nullptr, Cs, NSELF, As, Bs);
    } else {
        seg4<DIN>(g * RATIO + r, Pin, cnt, slots, G);
    }
}

// ---------------------------------------------------------------------------
// plain GEMM wrapper
// ---------------------------------------------------------------------------
template <bool A1F32, bool RELU, int OUTMODE, bool ADDC>
__global__ __launch_bounds__(256, 4) void gemm_k(
    const void* __restrict__ Av, const ushort* __restrict__ BT, int K,
    const float* __restrict__ bias, const ushort* __restrict__ cin,
    float* __restrict__ Cf, ushort* __restrict__ Cb, int N) {
    __shared__ __align__(16) ushort As[64 * AWK];
    __shared__ __align__(16) ushort Bs[64 * AWK];
    gemm_tile64<A1F32, RELU, OUTMODE, ADDC>(blockIdx.y, blockIdx.x, Av, BT, K,
                                            bias, cin, Cf, Cb, N, As, Bs);
}

// ---------------------------------------------------------------------------
// adj = H @ H^T, H [8192][64] bf16, C fp32. 128x128 tile, K=64 single stage.
// ---------------------------------------------------------------------------
__global__ __launch_bounds__(256) void aat_k(const ushort* __restrict__ H,
                                             float* __restrict__ C) {
    __shared__ __align__(16) ushort As[128 * 72];
    __shared__ __align__(16) ushort Bs[128 * 72];
    int tid = threadIdx.x, lane = tid & 63, wave = tid >> 6;
    int wm = (wave >> 1) * 64, wn = (wave & 1) * 64;
    int r16 = lane & 15, kb = lane >> 4;
    int m0 = blockIdx.y * 128, n0 = blockIdx.x * 128;

#pragma unroll
    for (int rep = 0; rep < 4; ++rep) {
        int id = rep * 256 + tid;
        int row = id >> 3, c = id & 7;
        *(bf16x8*)&As[row * 72 + c * 8] = *(const bf16x8*)&H[(size_t)(m0 + row) * 64 + c * 8];
        *(bf16x8*)&Bs[row * 72 + c * 8] = *(const bf16x8*)&H[(size_t)(n0 + row) * 64 + c * 8];
    }
    __syncthreads();

    f32x4 acc[4][4];
#pragma unroll
    for (int i = 0; i < 4; ++i)
#pragma unroll
        for (int j = 0; j < 4; ++j) acc[i][j] = (f32x4)(0.f);

#pragma unroll
    for (int kc = 0; kc < 2; ++kc) {
        bf16x8 a[4], b[4];
#pragma unroll
        for (int i = 0; i < 4; ++i)
            a[i] = *(const bf16x8*)&As[(wm + 16 * i + r16) * 72 + kc * 32 + kb * 8];
#pragma unroll
        for (int j = 0; j < 4; ++j)
            b[j] = *(const bf16x8*)&Bs[(wn + 16 * j + r16) * 72 + kc * 32 + kb * 8];
#pragma unroll
        for (int i = 0; i < 4; ++i)
#pragma unroll
            for (int j = 0; j < 4; ++j)
                acc[i][j] = __builtin_amdgcn_mfma_f32_16x16x32_bf16(a[i], b[j], acc[i][j], 0, 0, 0);
    }

#pragma unroll
    for (int i = 0; i < 4; ++i) {
#pragma unroll
        for (int j = 0; j < 4; ++j) {
            int col = n0 + wn + 16 * j + r16;
#pragma unroll
            for (int r = 0; r < 4; ++r) {
                size_t row = m0 + wm + 16 * i + kb * 4 + r;
                C[row * NN + col] = acc[i][j][r];
            }
        }
    }
}

// ---------------------------------------------------------------------------
extern "C" void kernel_launch(void* const* d_in, const int* in_sizes, int n_in,
                              void* d_out, int out_size, void* d_ws, size_t ws_size,
                              hipStream_t stream) {
    const float* feat = (const float*)d_in[0];
    const int* src = (const int*)d_in[1];
    const int* dst = (const int*)d_in[2];
    const float* ew = (const float*)d_in[3];
    const float* Wp1 = (const float*)d_in[5];
    const float* bp1 = (const float*)d_in[6];
    const float* Ws1 = (const float*)d_in[7];
    const float* Wn1 = (const float*)d_in[8];
    const float* b1  = (const float*)d_in[9];
    const float* Wp2 = (const float*)d_in[10];
    const float* bp2 = (const float*)d_in[11];
    const float* Ws2 = (const float*)d_in[12];
    const float* Wn2 = (const float*)d_in[13];
    const float* b2  = (const float*)d_in[14];
    const float* Wp3 = (const float*)d_in[15];
    const float* bp3 = (const float*)d_in[16];
    const float* Ws3 = (const float*)d_in[17];
    const float* Wn3 = (const float*)d_in[18];
    const float* b3  = (const float*)d_in[19];

    float* out = (float*)d_out;          // hd fp32 [8192][64]
    float* adj = out + (size_t)NN * 64;  // adj fp32 [8192][8192]

    char* ws = (char*)d_ws;
    int* cnt      = (int*)(ws + 0x0);          // 32 KB
    uint2* slots  = (uint2*)(ws + 0x10000);    // 6 MB
    ushort* Wp1T = (ushort*)(ws + 0x620000);
    ushort* Ws1T = (ushort*)(ws + 0x628000);
    ushort* Wn1T = (ushort*)(ws + 0x638000);
    ushort* Wp2T = (ushort*)(ws + 0x648000);
    ushort* Ws2T = (ushort*)(ws + 0x668000);
    ushort* Wn2T = (ushort*)(ws + 0x688000);
    ushort* Wp3T = (ushort*)(ws + 0x6A8000);
    ushort* Ws3T = (ushort*)(ws + 0x6C8000);
    ushort* Wn3T = (ushort*)(ws + 0x6D0000);
    ushort* P  = (ushort*)(ws + 0x700000);     // pool bf16 [N][<=256]
    ushort* G  = (ushort*)(ws + 0xB00000);     // agg bf16 [N][<=256]
    ushort* X  = (ushort*)(ws + 0xF00000);     // x2 bf16 [N][256]
    ushort* Y  = (ushort*)(ws + 0x1300000);    // x3 bf16 [N][256]
    ushort* Cs = (ushort*)(ws + 0x1700000);    // self bf16 [N][<=256]
    ushort* hdb = (ushort*)(ws + 0x1B00000);   // hd bf16 [N][64]

    // 1) prep: zero cnt + weight transposes
    PrepArgs pa;
    pa.cnt = cnt;
    const float* wsrc[9] = {Wp1, Ws1, Wn1, Wp2, Ws2, Wn2, Wp3, Ws3, Wn3};
    ushort* wdst[9] = {Wp1T, Ws1T, Wn1T, Wp2T, Ws2T, Wn2T, Wp3T, Ws3T, Wn3T};
    for (int i = 0; i < 9; ++i) { pa.w[i] = wsrc[i]; pa.wt[i] = wdst[i]; }
    prep_k<<<32 + 1472, 256, 0, stream>>>(pa);

    // 2) scatter || pool1 (interleaved)
    scat_pool1_k<<<1280, 256, 0, stream>>>(src, dst, ew, cnt, slots, feat, Wp1T, bp1, P);

    // layer 1 (128 -> 256)
    seg_self_k<128, 4, true, 128, 256><<<2560, 256, 0, stream>>>(
        P, cnt, slots, G, feat, Ws1T, b1, Cs);
    gemm_k<false, true, 0, true><<<dim3(4, 128), 256, 0, stream>>>(
        G, Wn1T, 128, nullptr, Cs, nullptr, X, 256);                  // X = relu(G@Wn1 + Cs)

    // layer 2 (256 -> 256)
    gemm_k<false, true, 0, false><<<dim3(4, 128), 256, 0, stream>>>(
        X, Wp2T, 256, bp2, nullptr, nullptr, P, 256);                 // pool2
    seg_self_k<256, 4, false, 256, 256><<<2560, 256, 0, stream>>>(
        P, cnt, slots, G, X, Ws2T, b2, Cs);
    gemm_k<false, true, 0, true><<<dim3(4, 128), 256, 0, stream>>>(
        G, Wn2T, 256, nullptr, Cs, nullptr, Y, 256);                  // Y

    // layer 3 (256 -> 64)
    gemm_k<false, true, 0, false><<<dim3(4, 128), 256, 0, stream>>>(
        Y, Wp3T, 256, bp3, nullptr, nullptr, P, 256);                 // pool3
    seg_self_k<256, 16, false, 256, 64><<<2176, 256, 0, stream>>>(
        P, cnt, slots, G, Y, Ws3T, b3, Cs);
    gemm_k<false, true, 2, true><<<dim3(1, 128), 256, 0, stream>>>(
        G, Wn3T, 256, nullptr, Cs, out, hdb, 64);                     // hd fp32 + bf16

    // adj = hd @ hd^T
    aat_k<<<dim3(NN / 128, NN / 128), 256, 0, stream>>>(hdb, adj);
}